// Round 1
// baseline (13758.931 us; speedup 1.0000x reference)
//
#include <hip/hip_runtime.h>
#include <cmath>

constexpr int B = 2, L = 4096, D = 256, H = 8, NC = 3;
constexpr int TOP_N = 8, R = 32;
constexpr int LS = 1000, LE = 3000;
constexpr int NL = 2;
constexpr int FF = 4 * D;                        // 1024
constexpr int Q_MAX = 2 * TOP_N * (2 * R + 1);   // 1040
constexpr int HD = D / H;                        // 32
constexpr int QROWS = B * Q_MAX;                 // 2080
constexpr int KVROWS = B * L;                    // 8192

// ---------------------------------------------------------------------------
// Kernel 1: vicinity selection. One block per batch.
// Computes top-8 positions for "don" (ch2) then "acc" (ch1) log-softmax within
// [LS,LE), builds 16x65 vicinity window, sorts, dedups (dups -> idx=L, mask=0).
// ---------------------------------------------------------------------------
__global__ __launch_bounds__(256) void select_kernel(
    const float* __restrict__ logits, int* __restrict__ idx_out,
    int* __restrict__ mask_out) {
  int b = blockIdx.x;
  int tid = threadIdx.x;
  __shared__ float red_v[256];
  __shared__ int red_i[256];
  __shared__ int centers[2 * TOP_N];
  __shared__ int vic[Q_MAX];
  __shared__ int s_sorted[Q_MAX];

  for (int sel = 0; sel < 2; ++sel) {
    int ch = (sel == 0) ? 2 : 1;  // don first, then acc
    for (int t = 0; t < TOP_N; ++t) {
      float bv = -INFINITY;
      int bi = L;
      for (int pos = LS + tid; pos < LE; pos += 256) {
        bool taken = false;
        for (int u = 0; u < t; ++u)
          if (centers[sel * TOP_N + u] == pos) taken = true;
        if (taken) continue;
        const float* lg = logits + ((long)b * L + pos) * NC;
        float x0 = lg[0], x1 = lg[1], x2 = lg[2];
        float m = fmaxf(x0, fmaxf(x1, x2));
        float lse = m + logf(expf(x0 - m) + expf(x1 - m) + expf(x2 - m));
        float v = ((ch == 2) ? x2 : x1) - lse;
        if (v > bv || (v == bv && pos < bi)) { bv = v; bi = pos; }
      }
      red_v[tid] = bv;
      red_i[tid] = bi;
      __syncthreads();
      for (int s = 128; s > 0; s >>= 1) {
        if (tid < s) {
          float ov = red_v[tid + s];
          int oi = red_i[tid + s];
          if (ov > red_v[tid] || (ov == red_v[tid] && oi < red_i[tid])) {
            red_v[tid] = ov;
            red_i[tid] = oi;
          }
        }
        __syncthreads();
      }
      if (tid == 0) centers[sel * TOP_N + t] = red_i[0];
      __syncthreads();
    }
  }

  for (int j = tid; j < Q_MAX; j += 256) {
    int c = centers[j / (2 * R + 1)];
    int off = j % (2 * R + 1) - R;
    int v = c + off;
    v = v < 0 ? 0 : (v > L - 1 ? L - 1 : v);
    vic[j] = v;
  }
  __syncthreads();

  // rank sort (stable)
  for (int j = tid; j < Q_MAX; j += 256) {
    int vj = vic[j];
    int rank = 0;
    for (int i = 0; i < Q_MAX; ++i) {
      int vi = vic[i];
      rank += (vi < vj) || (vi == vj && i < j);
    }
    s_sorted[rank] = vj;
  }
  __syncthreads();
  for (int j = tid; j < Q_MAX; j += 256) {
    bool first = (j == 0) || (s_sorted[j] != s_sorted[j - 1]);
    idx_out[b * Q_MAX + j] = first ? s_sorted[j] : L;
    mask_out[b * Q_MAX + j] = first ? 1 : 0;
  }
}

// ---------------------------------------------------------------------------
// Kernel 2: gather q_stream rows (pad row -> zeros)
// ---------------------------------------------------------------------------
__global__ __launch_bounds__(256) void gather_kernel(
    const float* __restrict__ enc, const int* __restrict__ idx,
    float* __restrict__ q_stream) {
  int row = blockIdx.x;
  int b = row / Q_MAX;
  int p = idx[row];
  float v = 0.f;
  if (p < L) v = enc[((long)b * L + p) * D + threadIdx.x];
  q_stream[(long)row * D + threadIdx.x] = v;
}

// ---------------------------------------------------------------------------
// LayerNorm: one block per row, D=256
// ---------------------------------------------------------------------------
__global__ __launch_bounds__(256) void ln_kernel(
    const float* __restrict__ in, float* __restrict__ out,
    const float* __restrict__ g, const float* __restrict__ bb) {
  long row = blockIdx.x;
  int tid = threadIdx.x;
  float x = in[row * D + tid];
  __shared__ float red[256];
  red[tid] = x;
  __syncthreads();
  for (int s = 128; s > 0; s >>= 1) {
    if (tid < s) red[tid] += red[tid + s];
    __syncthreads();
  }
  float mean = red[0] / D;
  __syncthreads();
  float d = x - mean;
  red[tid] = d * d;
  __syncthreads();
  for (int s = 128; s > 0; s >>= 1) {
    if (tid < s) red[tid] += red[tid + s];
    __syncthreads();
  }
  float var = red[0] / D;
  out[row * D + tid] = d * rsqrtf(var + 1e-5f) * g[tid] + bb[tid];
}

// ---------------------------------------------------------------------------
// Tiled fp32 GEMM: C[M,N] = epi(A[M,K] @ W[K,N] + bias)
// EPI 0: bias only; 1: gelu(x); 2: mask[row] ? resid[row,col] + x : 0
// 64x64 tile, BK=16, 256 threads, 4x4 per thread.
// ---------------------------------------------------------------------------
__device__ __forceinline__ float gelu_exact(float x) {
  return 0.5f * x * (1.f + erff(x * 0.70710678118654752440f));
}

template <int EPI>
__global__ __launch_bounds__(256) void gemm_kernel(
    const float* __restrict__ A, const float* __restrict__ W,
    const float* __restrict__ bias, float* __restrict__ Cout,
    const float* __restrict__ resid, const int* __restrict__ mask, int M,
    int N, int K) {
  __shared__ float As[16][68];
  __shared__ float Ws[16][68];
  int bm = blockIdx.y * 64, bn = blockIdx.x * 64;
  int tid = threadIdx.x;
  int tm0 = (tid >> 4) << 2, tn0 = (tid & 15) << 2;
  float acc[4][4] = {};

  for (int k0 = 0; k0 < K; k0 += 16) {
    {
      int c = tid & 15, r = tid >> 4;
      for (int rr = r; rr < 64; rr += 16) {
        int row = bm + rr;
        As[c][rr] = (row < M) ? A[(long)row * K + k0 + c] : 0.f;
      }
    }
    {
      int c = tid & 63, r = tid >> 6;
      for (int rr = r; rr < 16; rr += 4)
        Ws[rr][c] = W[(long)(k0 + rr) * N + bn + c];
    }
    __syncthreads();
#pragma unroll
    for (int k = 0; k < 16; ++k) {
      float a0 = As[k][tm0], a1 = As[k][tm0 + 1], a2 = As[k][tm0 + 2],
            a3 = As[k][tm0 + 3];
      float b0 = Ws[k][tn0], b1 = Ws[k][tn0 + 1], b2 = Ws[k][tn0 + 2],
            b3 = Ws[k][tn0 + 3];
      acc[0][0] += a0 * b0; acc[0][1] += a0 * b1; acc[0][2] += a0 * b2; acc[0][3] += a0 * b3;
      acc[1][0] += a1 * b0; acc[1][1] += a1 * b1; acc[1][2] += a1 * b2; acc[1][3] += a1 * b3;
      acc[2][0] += a2 * b0; acc[2][1] += a2 * b1; acc[2][2] += a2 * b2; acc[2][3] += a2 * b3;
      acc[3][0] += a3 * b0; acc[3][1] += a3 * b1; acc[3][2] += a3 * b2; acc[3][3] += a3 * b3;
    }
    __syncthreads();
  }

#pragma unroll
  for (int i = 0; i < 4; ++i) {
    int row = bm + tm0 + i;
    if (row >= M) continue;
#pragma unroll
    for (int j = 0; j < 4; ++j) {
      int col = bn + tn0 + j;
      float v = acc[i][j] + bias[col];
      if (EPI == 1) v = gelu_exact(v);
      if (EPI == 2) {
        v += resid[(long)row * N + col];
        v = mask[row] ? v : 0.f;
      }
      Cout[(long)row * N + col] = v;
    }
  }
}

// ---------------------------------------------------------------------------
// Attention: one wave per (b, h, q). Two-pass softmax, scores in LDS.
// ---------------------------------------------------------------------------
__global__ __launch_bounds__(64) void attn_kernel(
    const float* __restrict__ Qb, const float* __restrict__ Kb,
    const float* __restrict__ Vb, float* __restrict__ AO) {
  int blk = blockIdx.x;
  int q = blk % Q_MAX;
  int bh = blk / Q_MAX;
  int h = bh % H;
  int b = bh / H;
  int lane = threadIdx.x;
  __shared__ float sc[L];
  __shared__ float qs[HD];

  long qoff = ((long)b * Q_MAX + q) * D + h * HD;
  if (lane < HD) qs[lane] = Qb[qoff + lane];
  __syncthreads();

  int d = lane & 31, half = lane >> 5;
  const float scale = 0.17677669529663687f;  // 1/sqrt(32)
  float qd = qs[d];
  long kvbase = ((long)b * L) * D + h * HD + d;

  float lmax = -INFINITY;
  for (int k0 = 0; k0 < L; k0 += 2) {
    int key = k0 + half;
    float p = qd * Kb[kvbase + (long)key * D];
    p += __shfl_xor(p, 16, 32);
    p += __shfl_xor(p, 8, 32);
    p += __shfl_xor(p, 4, 32);
    p += __shfl_xor(p, 2, 32);
    p += __shfl_xor(p, 1, 32);
    p *= scale;
    if (d == 0) sc[key] = p;
    lmax = fmaxf(lmax, p);
  }
  lmax = fmaxf(lmax, __shfl_xor(lmax, 32, 64));
  __syncthreads();

  float denom = 0.f, acc = 0.f;
  for (int k0 = 0; k0 < L; k0 += 2) {
    int key = k0 + half;
    float e = __expf(sc[key] - lmax);
    denom += e;
    acc += e * Vb[kvbase + (long)key * D];
  }
  denom += __shfl_xor(denom, 32, 64);
  acc += __shfl_xor(acc, 32, 64);
  if (half == 0) AO[qoff + d] = acc / denom;
}

// ---------------------------------------------------------------------------
// Head over all rows: out[row, c] = enc[row,:] @ head_W[:,c] + head_b[c]
// ---------------------------------------------------------------------------
__global__ __launch_bounds__(256) void head_kernel(
    const float* __restrict__ enc, const float* __restrict__ hW,
    const float* __restrict__ hb, float* __restrict__ out) {
  __shared__ float Ws[D * NC];
  for (int i = threadIdx.x; i < D * NC; i += 256) Ws[i] = hW[i];
  __syncthreads();
  long row = (long)blockIdx.x * 256 + threadIdx.x;
  const float* a = enc + row * D;
  float c0 = hb[0], c1 = hb[1], c2 = hb[2];
  for (int k = 0; k < D; ++k) {
    float av = a[k];
    c0 += av * Ws[k * 3];
    c1 += av * Ws[k * 3 + 1];
    c2 += av * Ws[k * 3 + 2];
  }
  out[row * 3] = c0;
  out[row * 3 + 1] = c1;
  out[row * 3 + 2] = c2;
}

// ---------------------------------------------------------------------------
// Overwrite selected rows with refined head output. One wave per slot.
// ---------------------------------------------------------------------------
__global__ __launch_bounds__(64) void overwrite_kernel(
    const float* __restrict__ q_stream, const int* __restrict__ idx,
    const int* __restrict__ mask, const float* __restrict__ hW,
    const float* __restrict__ hb, float* __restrict__ out) {
  int j = blockIdx.x;
  if (!mask[j]) return;
  int b = j / Q_MAX;
  int p = idx[j];
  int lane = threadIdx.x;
  const float* a = q_stream + (long)j * D;
  float a0 = a[lane], a1 = a[lane + 64], a2 = a[lane + 128],
        a3 = a[lane + 192];
  for (int c = 0; c < 3; ++c) {
    float s = a0 * hW[lane * 3 + c] + a1 * hW[(lane + 64) * 3 + c] +
              a2 * hW[(lane + 128) * 3 + c] + a3 * hW[(lane + 192) * 3 + c];
    for (int off = 32; off > 0; off >>= 1) s += __shfl_down(s, off, 64);
    if (lane == 0) out[((long)b * L + p) * 3 + c] = s + hb[c];
  }
}

// ---------------------------------------------------------------------------
extern "C" void kernel_launch(void* const* d_in, const int* in_sizes, int n_in,
                              void* d_out, int out_size, void* d_ws,
                              size_t ws_size, hipStream_t stream) {
  const float* enc = (const float*)d_in[0];
  const float* clog = (const float*)d_in[1];
  const float* ln_q_g = (const float*)d_in[2];
  const float* ln_q_b = (const float*)d_in[3];
  const float* ln_kv_g = (const float*)d_in[4];
  const float* ln_kv_b = (const float*)d_in[5];
  const float* Wq = (const float*)d_in[6];
  const float* bq = (const float*)d_in[7];
  const float* Wk = (const float*)d_in[8];
  const float* bk = (const float*)d_in[9];
  const float* Wv = (const float*)d_in[10];
  const float* bv = (const float*)d_in[11];
  const float* Wo = (const float*)d_in[12];
  const float* bo = (const float*)d_in[13];
  const float* ffn_g = (const float*)d_in[14];
  const float* ffn_b = (const float*)d_in[15];
  const float* W1 = (const float*)d_in[16];
  const float* b1 = (const float*)d_in[17];
  const float* W2 = (const float*)d_in[18];
  const float* b2 = (const float*)d_in[19];
  const float* head_W = (const float*)d_in[20];
  const float* head_b = (const float*)d_in[21];
  float* out = (float*)d_out;

  float* ws = (float*)d_ws;
  float* q_stream = ws;                         // QROWS*D
  float* kv_ln = q_stream + (long)QROWS * D;    // KVROWS*D
  float* Kbuf = kv_ln + (long)KVROWS * D;       // KVROWS*D
  float* Vbuf = Kbuf + (long)KVROWS * D;        // KVROWS*D
  float* q_ln = Vbuf + (long)KVROWS * D;        // QROWS*D
  float* Qbuf = q_ln + (long)QROWS * D;         // QROWS*D
  float* AObuf = Qbuf + (long)QROWS * D;        // QROWS*D
  float* H1buf = AObuf + (long)QROWS * D;       // QROWS*FF
  int* idxbuf = (int*)(H1buf + (long)QROWS * FF);
  int* maskbuf = idxbuf + QROWS;

  select_kernel<<<B, 256, 0, stream>>>(clog, idxbuf, maskbuf);
  gather_kernel<<<QROWS, 256, 0, stream>>>(enc, idxbuf, q_stream);

  for (int layer = 0; layer < NL; ++layer) {
    ln_kernel<<<KVROWS, 256, 0, stream>>>(enc, kv_ln, ln_kv_g + layer * D,
                                          ln_kv_b + layer * D);
    ln_kernel<<<QROWS, 256, 0, stream>>>(q_stream, q_ln, ln_q_g + layer * D,
                                         ln_q_b + layer * D);

    dim3 gKV(256 / 64, (KVROWS + 63) / 64);
    gemm_kernel<0><<<gKV, 256, 0, stream>>>(kv_ln, Wk + (long)layer * D * D,
                                            bk + layer * D, Kbuf, nullptr,
                                            nullptr, KVROWS, D, D);
    gemm_kernel<0><<<gKV, 256, 0, stream>>>(kv_ln, Wv + (long)layer * D * D,
                                            bv + layer * D, Vbuf, nullptr,
                                            nullptr, KVROWS, D, D);
    dim3 gQ(256 / 64, (QROWS + 63) / 64);
    gemm_kernel<0><<<gQ, 256, 0, stream>>>(q_ln, Wq + (long)layer * D * D,
                                           bq + layer * D, Qbuf, nullptr,
                                           nullptr, QROWS, D, D);

    attn_kernel<<<B * H * Q_MAX, 64, 0, stream>>>(Qbuf, Kbuf, Vbuf, AObuf);

    // q_stream = mask ? q_stream + AO @ Wo + bo : 0
    gemm_kernel<2><<<gQ, 256, 0, stream>>>(AObuf, Wo + (long)layer * D * D,
                                           bo + layer * D, q_stream, q_stream,
                                           maskbuf, QROWS, D, D);

    ln_kernel<<<QROWS, 256, 0, stream>>>(q_stream, q_ln, ffn_g + layer * D,
                                         ffn_b + layer * D);
    dim3 gF1(FF / 64, (QROWS + 63) / 64);
    gemm_kernel<1><<<gF1, 256, 0, stream>>>(q_ln, W1 + (long)layer * D * FF,
                                            b1 + layer * FF, H1buf, nullptr,
                                            nullptr, QROWS, FF, D);
    dim3 gF2(256 / 64, (QROWS + 63) / 64);
    gemm_kernel<2><<<gF2, 256, 0, stream>>>(H1buf, W2 + (long)layer * FF * D,
                                            b2 + layer * D, q_stream, q_stream,
                                            maskbuf, QROWS, D, FF);
  }

  head_kernel<<<KVROWS / 256, 256, 0, stream>>>(enc, head_W, head_b, out);
  overwrite_kernel<<<QROWS, 64, 0, stream>>>(q_stream, idxbuf, maskbuf, head_W,
                                             head_b, out);
}

// Round 2
// 490.830 us; speedup vs baseline: 28.0320x; 28.0320x over previous
//
#include <hip/hip_runtime.h>
#include <cmath>

constexpr int B = 2, L = 4096, D = 256, H = 8, NC = 3;
constexpr int TOP_N = 8, R = 32;
constexpr int LS = 1000, LE = 3000;
constexpr int NL = 2;
constexpr int FF = 4 * D;                        // 1024
constexpr int Q_MAX = 2 * TOP_N * (2 * R + 1);   // 1040
constexpr int HD = D / H;                        // 32
constexpr int QROWS = B * Q_MAX;                 // 2080
constexpr int KVROWS = B * L;                    // 8192
constexpr int QT_TILES = (Q_MAX + 63) / 64;      // 17
constexpr int NREG = LE - LS;                    // 2000

typedef __attribute__((ext_vector_type(8))) short bf16x8;
typedef __attribute__((ext_vector_type(4))) float f32x4;
typedef unsigned short u16;

__device__ __forceinline__ u16 f2bs(float f) {
  unsigned int u = __float_as_uint(f);
  unsigned int r = u + 0x7fffu + ((u >> 16) & 1u);
  return (u16)(r >> 16);
}
__device__ __forceinline__ float bs2f(u16 s) {
  return __uint_as_float(((unsigned int)s) << 16);
}
__device__ __forceinline__ float gelu_exact(float x) {
  return 0.5f * x * (1.f + erff(x * 0.70710678118654752440f));
}

// ---------------------------------------------------------------------------
// Vicinity selection. One block of 1024 threads per batch.
// ---------------------------------------------------------------------------
__global__ __launch_bounds__(1024) void select_kernel(
    const float* __restrict__ logits, int* __restrict__ idx_out,
    int* __restrict__ mask_out) {
  int b = blockIdx.x;
  int tid = threadIdx.x;
  __shared__ float v1[NREG], v2[NREG];
  __shared__ float red_v[1024];
  __shared__ int red_i[1024];
  __shared__ int centers[2 * TOP_N];
  __shared__ int vic[Q_MAX];
  __shared__ int s_sorted[Q_MAX];

  for (int p = tid; p < NREG; p += 1024) {
    const float* lg = logits + ((long)b * L + LS + p) * NC;
    float x0 = lg[0], x1 = lg[1], x2 = lg[2];
    float m = fmaxf(x0, fmaxf(x1, x2));
    float lse = m + logf(expf(x0 - m) + expf(x1 - m) + expf(x2 - m));
    v2[p] = x2 - lse;
    v1[p] = x1 - lse;
  }
  __syncthreads();

  for (int sel = 0; sel < 2; ++sel) {
    float* vv = (sel == 0) ? v2 : v1;  // don (ch2) first, then acc (ch1)
    for (int t = 0; t < TOP_N; ++t) {
      float bv = -INFINITY;
      int bi = NREG;
      for (int p = tid; p < NREG; p += 1024) {
        float x = vv[p];
        if (x > bv) { bv = x; bi = p; }
      }
      red_v[tid] = bv;
      red_i[tid] = bi;
      __syncthreads();
      for (int s = 512; s > 0; s >>= 1) {
        if (tid < s) {
          float ov = red_v[tid + s];
          int oi = red_i[tid + s];
          if (ov > red_v[tid] || (ov == red_v[tid] && oi < red_i[tid])) {
            red_v[tid] = ov;
            red_i[tid] = oi;
          }
        }
        __syncthreads();
      }
      if (tid == 0) {
        centers[sel * TOP_N + t] = LS + red_i[0];
        vv[red_i[0]] = -INFINITY;
      }
      __syncthreads();
    }
  }

  for (int j = tid; j < Q_MAX; j += 1024) {
    int c = centers[j / (2 * R + 1)];
    int off = j % (2 * R + 1) - R;
    int v = c + off;
    v = v < 0 ? 0 : (v > L - 1 ? L - 1 : v);
    vic[j] = v;
  }
  __syncthreads();
  for (int j = tid; j < Q_MAX; j += 1024) {
    int vj = vic[j];
    int rank = 0;
    for (int i = 0; i < Q_MAX; ++i) {
      int vi = vic[i];
      rank += (vi < vj) || (vi == vj && i < j);
    }
    s_sorted[rank] = vj;
  }
  __syncthreads();
  for (int j = tid; j < Q_MAX; j += 1024) {
    bool first = (j == 0) || (s_sorted[j] != s_sorted[j - 1]);
    idx_out[b * Q_MAX + j] = first ? s_sorted[j] : L;
    mask_out[b * Q_MAX + j] = first ? 1 : 0;
  }
}

// ---------------------------------------------------------------------------
// Gather q_stream rows (pad row -> zeros); fp32 residual stream
// ---------------------------------------------------------------------------
__global__ __launch_bounds__(256) void gather_kernel(
    const float* __restrict__ enc, const int* __restrict__ idx,
    float* __restrict__ q_stream) {
  int row = blockIdx.x;
  int b = row / Q_MAX;
  int p = idx[row];
  float v = 0.f;
  if (p < L) v = enc[((long)b * L + p) * D + threadIdx.x];
  q_stream[(long)row * D + threadIdx.x] = v;
}

// ---------------------------------------------------------------------------
// LayerNorm fp32 in -> bf16 out. One block (256 thr) per row.
// ---------------------------------------------------------------------------
__global__ __launch_bounds__(256) void ln_bf16(
    const float* __restrict__ in, u16* __restrict__ out,
    const float* __restrict__ gg, const float* __restrict__ bb) {
  long row = blockIdx.x;
  int tid = threadIdx.x;
  float x = in[row * D + tid];
  float s1 = x, s2 = x * x;
#pragma unroll
  for (int off = 32; off; off >>= 1) {
    s1 += __shfl_xor(s1, off, 64);
    s2 += __shfl_xor(s2, off, 64);
  }
  __shared__ float p1[4], p2[4];
  int w = tid >> 6;
  if ((tid & 63) == 0) { p1[w] = s1; p2[w] = s2; }
  __syncthreads();
  s1 = p1[0] + p1[1] + p1[2] + p1[3];
  s2 = p2[0] + p2[1] + p2[2] + p2[3];
  float mean = s1 * (1.f / D);
  float var = fmaxf(s2 * (1.f / D) - mean * mean, 0.f);
  float r = rsqrtf(var + 1e-5f);
  out[row * D + tid] = f2bs((x - mean) * r * gg[tid] + bb[tid]);
}

// ---------------------------------------------------------------------------
// Transpose + bf16-convert a weight matrix: WT[n*K + k] = bf16(W[k*N + n])
// ---------------------------------------------------------------------------
__global__ __launch_bounds__(256) void transpose_w(
    const float* __restrict__ W, u16* __restrict__ WT, int K, int N) {
  long t = (long)blockIdx.x * 256 + threadIdx.x;
  if (t < (long)K * N) {
    int k = (int)(t / N), n = (int)(t % N);
    WT[(long)n * K + k] = f2bs(W[t]);
  }
}

// ---------------------------------------------------------------------------
// bf16 MFMA GEMM: C[M,N] = epi(A[M,K] @ B + bias), B given as BT[N,K] bf16.
// 64x64 tile, BK=32, 256 threads (4 waves, each a 32x32 quadrant of 2x2
// 16x16x32 MFMAs). EPI 0: bias; 1: gelu; 2: resid+mask. OB: bf16 out.
// ---------------------------------------------------------------------------
template <int EPI, bool OB>
__global__ __launch_bounds__(256) void gemm_mfma(
    const u16* __restrict__ A, const u16* __restrict__ BT,
    const float* __restrict__ bias, void* __restrict__ Cv,
    const float* __restrict__ resid, const int* __restrict__ mask, int M,
    int N, int K) {
  __shared__ short As[64][40];
  __shared__ short Bs[64][40];
  int bm = blockIdx.y * 64, bn = blockIdx.x * 64;
  int tid = threadIdx.x;
  int lane = tid & 63, w = tid >> 6;
  int g = lane >> 4, li = lane & 15;
  int wr = w >> 1, wc = w & 1;
  f32x4 acc[2][2] = {};

  int srow = tid >> 2, skc = (tid & 3) * 8;
  for (int k0 = 0; k0 < K; k0 += 32) {
    {
      int grow = bm + srow;
      bf16x8 av = {};
      if (grow < M)
        av = *reinterpret_cast<const bf16x8*>(A + (long)grow * K + k0 + skc);
      *reinterpret_cast<bf16x8*>(&As[srow][skc]) = av;
      bf16x8 bv = *reinterpret_cast<const bf16x8*>(
          BT + (long)(bn + srow) * K + k0 + skc);
      *reinterpret_cast<bf16x8*>(&Bs[srow][skc]) = bv;
    }
    __syncthreads();
    bf16x8 a0 = *reinterpret_cast<const bf16x8*>(&As[wr * 32 + li][g * 8]);
    bf16x8 a1 = *reinterpret_cast<const bf16x8*>(&As[wr * 32 + 16 + li][g * 8]);
    bf16x8 b0 = *reinterpret_cast<const bf16x8*>(&Bs[wc * 32 + li][g * 8]);
    bf16x8 b1 = *reinterpret_cast<const bf16x8*>(&Bs[wc * 32 + 16 + li][g * 8]);
    acc[0][0] = __builtin_amdgcn_mfma_f32_16x16x32_bf16(a0, b0, acc[0][0], 0, 0, 0);
    acc[0][1] = __builtin_amdgcn_mfma_f32_16x16x32_bf16(a0, b1, acc[0][1], 0, 0, 0);
    acc[1][0] = __builtin_amdgcn_mfma_f32_16x16x32_bf16(a1, b0, acc[1][0], 0, 0, 0);
    acc[1][1] = __builtin_amdgcn_mfma_f32_16x16x32_bf16(a1, b1, acc[1][1], 0, 0, 0);
    __syncthreads();
  }

#pragma unroll
  for (int mr = 0; mr < 2; ++mr)
#pragma unroll
    for (int nr = 0; nr < 2; ++nr)
#pragma unroll
      for (int r = 0; r < 4; ++r) {
        int row = bm + wr * 32 + mr * 16 + g * 4 + r;
        int col = bn + wc * 32 + nr * 16 + li;
        if (row >= M) continue;
        float v = acc[mr][nr][r] + bias[col];
        if (EPI == 1) v = gelu_exact(v);
        if (EPI == 2) {
          v += resid[(long)row * N + col];
          v = mask[row] ? v : 0.f;
        }
        if (OB)
          ((u16*)Cv)[(long)row * N + col] = f2bs(v);
        else
          ((float*)Cv)[(long)row * N + col] = v;
      }
}

// ---------------------------------------------------------------------------
// Fused flash attention, bf16 MFMA. Block = 256 thr (4 waves), each wave owns
// 16 queries of a 64-query tile for one (b,h). Swapped QK^T (mfma(K,Q)->S^T)
// keeps P lane-local; V read from LDS in matching k-order for PV.
// ---------------------------------------------------------------------------
__global__ __launch_bounds__(256) void attn_mfma(
    const u16* __restrict__ Q, const u16* __restrict__ Kb,
    const u16* __restrict__ Vb, u16* __restrict__ AO) {
  int bid = blockIdx.x;
  int qt = bid % QT_TILES;
  int bh = bid / QT_TILES;
  int h = bh % H;
  int b = bh / H;
  int tid = threadIdx.x;
  int lane = tid & 63, w = tid >> 6;
  int g = lane >> 4, li = lane & 15;
  __shared__ short Ks[32][40];
  __shared__ short Vs[32][40];

  // Q fragment (B-operand), pre-scaled by 1/sqrt(HD)
  int qrow = qt * 64 + w * 16 + li;
  int qc = qrow < Q_MAX ? qrow : Q_MAX - 1;
  bf16x8 qf;
  {
    const u16* qp = Q + ((long)(b * Q_MAX + qc)) * D + h * HD + g * 8;
    bf16x8 raw = *reinterpret_cast<const bf16x8*>(qp);
#pragma unroll
    for (int j = 0; j < 8; ++j)
      qf[j] = (short)f2bs(bs2f((u16)raw[j]) * 0.17677669529663687f);
  }

  f32x4 acc0 = {}, acc1 = {};
  float mrun = -INFINITY, den = 0.f;
  int srow = tid >> 3, sch = (tid & 7) * 4;
  const f32x4 zero = {};

  for (int kb = 0; kb < L; kb += 32) {
    {
      long base = ((long)(b * L + kb + srow)) * D + h * HD + sch;
      *(unsigned long long*)(&Ks[srow][sch]) =
          *(const unsigned long long*)(Kb + base);
      *(unsigned long long*)(&Vs[srow][sch]) =
          *(const unsigned long long*)(Vb + base);
    }
    __syncthreads();

    bf16x8 k0 = *reinterpret_cast<const bf16x8*>(&Ks[li][g * 8]);
    bf16x8 k1 = *reinterpret_cast<const bf16x8*>(&Ks[16 + li][g * 8]);
    f32x4 st0 = __builtin_amdgcn_mfma_f32_16x16x32_bf16(k0, qf, zero, 0, 0, 0);
    f32x4 st1 = __builtin_amdgcn_mfma_f32_16x16x32_bf16(k1, qf, zero, 0, 0, 0);

    float tmax = fmaxf(fmaxf(fmaxf(st0[0], st0[1]), fmaxf(st0[2], st0[3])),
                       fmaxf(fmaxf(st1[0], st1[1]), fmaxf(st1[2], st1[3])));
    tmax = fmaxf(tmax, __shfl_xor(tmax, 16, 64));
    tmax = fmaxf(tmax, __shfl_xor(tmax, 32, 64));
    float nm = fmaxf(mrun, tmax);
    float sc = __expf(mrun - nm);
    mrun = nm;
    float p[8];
    float tsum = 0.f;
#pragma unroll
    for (int r = 0; r < 4; ++r) {
      p[r] = __expf(st0[r] - nm);
      p[4 + r] = __expf(st1[r] - nm);
      tsum += p[r] + p[4 + r];
    }
    tsum += __shfl_xor(tsum, 16, 64);
    tsum += __shfl_xor(tsum, 32, 64);
    den = den * sc + tsum;
#pragma unroll
    for (int r = 0; r < 4; ++r) { acc0[r] *= sc; acc1[r] *= sc; }

    bf16x8 pf;
#pragma unroll
    for (int j = 0; j < 8; ++j) pf[j] = (short)f2bs(p[j]);

    bf16x8 v0, v1;
#pragma unroll
    for (int j = 0; j < 8; ++j) {
      int kk = (j < 4) ? (g * 4 + j) : (16 + g * 4 + (j - 4));
      v0[j] = Vs[kk][li];
      v1[j] = Vs[kk][16 + li];
    }
    acc0 = __builtin_amdgcn_mfma_f32_16x16x32_bf16(v0, pf, acc0, 0, 0, 0);
    acc1 = __builtin_amdgcn_mfma_f32_16x16x32_bf16(v1, pf, acc1, 0, 0, 0);
    __syncthreads();
  }

  float rden = 1.f / den;
  if (qrow < Q_MAX) {
    u16* op = AO + ((long)(b * Q_MAX + qrow)) * D + h * HD;
#pragma unroll
    for (int r = 0; r < 4; ++r) {
      op[g * 4 + r] = f2bs(acc0[r] * rden);
      op[16 + g * 4 + r] = f2bs(acc1[r] * rden);
    }
  }
}

// ---------------------------------------------------------------------------
// Head over all rows; one wave per row (float4 loads, shuffle reduce)
// ---------------------------------------------------------------------------
__global__ __launch_bounds__(256) void head_kernel(
    const float* __restrict__ enc, const float* __restrict__ hW,
    const float* __restrict__ hb, float* __restrict__ out) {
  int row = blockIdx.x * 4 + (threadIdx.x >> 6);
  int lane = threadIdx.x & 63;
  const float4 a = *reinterpret_cast<const float4*>(enc + (long)row * D + lane * 4);
  float c0 = 0.f, c1 = 0.f, c2 = 0.f;
  const float av[4] = {a.x, a.y, a.z, a.w};
#pragma unroll
  for (int i = 0; i < 4; ++i) {
    int k = lane * 4 + i;
    c0 += av[i] * hW[k * 3];
    c1 += av[i] * hW[k * 3 + 1];
    c2 += av[i] * hW[k * 3 + 2];
  }
#pragma unroll
  for (int off = 32; off; off >>= 1) {
    c0 += __shfl_down(c0, off, 64);
    c1 += __shfl_down(c1, off, 64);
    c2 += __shfl_down(c2, off, 64);
  }
  if (lane == 0) {
    out[(long)row * 3] = c0 + hb[0];
    out[(long)row * 3 + 1] = c1 + hb[1];
    out[(long)row * 3 + 2] = c2 + hb[2];
  }
}

// ---------------------------------------------------------------------------
// Overwrite selected rows with head(q_stream). One wave per slot.
// ---------------------------------------------------------------------------
__global__ __launch_bounds__(64) void overwrite_kernel(
    const float* __restrict__ q_stream, const int* __restrict__ idx,
    const int* __restrict__ mask, const float* __restrict__ hW,
    const float* __restrict__ hb, float* __restrict__ out) {
  int j = blockIdx.x;
  if (!mask[j]) return;
  int b = j / Q_MAX;
  int p = idx[j];
  int lane = threadIdx.x;
  const float* a = q_stream + (long)j * D;
  float a0 = a[lane], a1 = a[lane + 64], a2 = a[lane + 128],
        a3 = a[lane + 192];
  for (int c = 0; c < 3; ++c) {
    float s = a0 * hW[lane * 3 + c] + a1 * hW[(lane + 64) * 3 + c] +
              a2 * hW[(lane + 128) * 3 + c] + a3 * hW[(lane + 192) * 3 + c];
    for (int off = 32; off > 0; off >>= 1) s += __shfl_down(s, off, 64);
    if (lane == 0) out[((long)b * L + p) * 3 + c] = s + hb[c];
  }
}

// ---------------------------------------------------------------------------
extern "C" void kernel_launch(void* const* d_in, const int* in_sizes, int n_in,
                              void* d_out, int out_size, void* d_ws,
                              size_t ws_size, hipStream_t stream) {
  const float* enc = (const float*)d_in[0];
  const float* clog = (const float*)d_in[1];
  const float* ln_q_g = (const float*)d_in[2];
  const float* ln_q_b = (const float*)d_in[3];
  const float* ln_kv_g = (const float*)d_in[4];
  const float* ln_kv_b = (const float*)d_in[5];
  const float* Wq = (const float*)d_in[6];
  const float* bq = (const float*)d_in[7];
  const float* Wk = (const float*)d_in[8];
  const float* bk = (const float*)d_in[9];
  const float* Wv = (const float*)d_in[10];
  const float* bv = (const float*)d_in[11];
  const float* Wo = (const float*)d_in[12];
  const float* bo = (const float*)d_in[13];
  const float* ffn_g = (const float*)d_in[14];
  const float* ffn_b = (const float*)d_in[15];
  const float* W1 = (const float*)d_in[16];
  const float* b1 = (const float*)d_in[17];
  const float* W2 = (const float*)d_in[18];
  const float* b2 = (const float*)d_in[19];
  const float* head_W = (const float*)d_in[20];
  const float* head_b = (const float*)d_in[21];
  float* out = (float*)d_out;

  char* ws = (char*)d_ws;
  float* q_stream = (float*)ws;            ws += (long)QROWS * D * 4;
  u16* kv_ln = (u16*)ws;                   ws += (long)KVROWS * D * 2;
  u16* Kbuf = (u16*)ws;                    ws += (long)KVROWS * D * 2;
  u16* Vbuf = (u16*)ws;                    ws += (long)KVROWS * D * 2;
  u16* q_ln = (u16*)ws;                    ws += (long)QROWS * D * 2;
  u16* Qbuf = (u16*)ws;                    ws += (long)QROWS * D * 2;
  u16* AObuf = (u16*)ws;                   ws += (long)QROWS * D * 2;
  u16* H1buf = (u16*)ws;                   ws += (long)QROWS * FF * 2;
  u16* WT = (u16*)ws;                      ws += (long)NL * (4 * D * D + 2 * D * FF) * 2;
  int* idxbuf = (int*)ws;                  ws += QROWS * 4;
  int* maskbuf = (int*)ws;

  const long LSTRIDE = 4 * D * D + 2 * D * FF;  // shorts per layer: 786432
  // Per-layer WT offsets (shorts): Wk 0, Wv DD, Wq 2DD, Wo 3DD, W1 4DD, W2 4DD+DFF
  const long DD = (long)D * D, DFF = (long)D * FF;

  // Pre-transpose all weights to bf16 [N][K]
  for (int l = 0; l < NL; ++l) {
    u16* base = WT + l * LSTRIDE;
    transpose_w<<<(DD + 255) / 256, 256, 0, stream>>>(Wk + l * DD, base, D, D);
    transpose_w<<<(DD + 255) / 256, 256, 0, stream>>>(Wv + l * DD, base + DD, D, D);
    transpose_w<<<(DD + 255) / 256, 256, 0, stream>>>(Wq + l * DD, base + 2 * DD, D, D);
    transpose_w<<<(DD + 255) / 256, 256, 0, stream>>>(Wo + l * DD, base + 3 * DD, D, D);
    transpose_w<<<(DFF + 255) / 256, 256, 0, stream>>>(W1 + l * DFF, base + 4 * DD, D, FF);
    transpose_w<<<(DFF + 255) / 256, 256, 0, stream>>>(W2 + l * DFF, base + 4 * DD + DFF, FF, D);
  }

  select_kernel<<<B, 1024, 0, stream>>>(clog, idxbuf, maskbuf);
  gather_kernel<<<QROWS, 256, 0, stream>>>(enc, idxbuf, q_stream);

  for (int l = 0; l < NL; ++l) {
    u16* base = WT + l * LSTRIDE;
    ln_bf16<<<KVROWS, 256, 0, stream>>>(enc, kv_ln, ln_kv_g + l * D, ln_kv_b + l * D);
    ln_bf16<<<QROWS, 256, 0, stream>>>(q_stream, q_ln, ln_q_g + l * D, ln_q_b + l * D);

    dim3 gKV(D / 64, KVROWS / 64);
    gemm_mfma<0, true><<<gKV, 256, 0, stream>>>(kv_ln, base, bk + l * D,
                                                (void*)Kbuf, nullptr, nullptr,
                                                KVROWS, D, D);
    gemm_mfma<0, true><<<gKV, 256, 0, stream>>>(kv_ln, base + DD, bv + l * D,
                                                (void*)Vbuf, nullptr, nullptr,
                                                KVROWS, D, D);
    dim3 gQ(D / 64, (QROWS + 63) / 64);
    gemm_mfma<0, true><<<gQ, 256, 0, stream>>>(q_ln, base + 2 * DD, bq + l * D,
                                               (void*)Qbuf, nullptr, nullptr,
                                               QROWS, D, D);

    attn_mfma<<<B * H * QT_TILES, 256, 0, stream>>>(Qbuf, Kbuf, Vbuf, AObuf);

    gemm_mfma<2, false><<<gQ, 256, 0, stream>>>(AObuf, base + 3 * DD,
                                                bo + l * D, (void*)q_stream,
                                                q_stream, maskbuf, QROWS, D, D);

    ln_bf16<<<QROWS, 256, 0, stream>>>(q_stream, q_ln, ffn_g + l * D, ffn_b + l * D);
    dim3 gF1(FF / 64, (QROWS + 63) / 64);
    gemm_mfma<1, true><<<gF1, 256, 0, stream>>>(q_ln, base + 4 * DD,
                                                b1 + l * FF, (void*)H1buf,
                                                nullptr, nullptr, QROWS, FF, D);
    dim3 gF2(D / 64, (QROWS + 63) / 64);
    gemm_mfma<2, false><<<gF2, 256, 0, stream>>>(H1buf, base + 4 * DD + DFF,
                                                 b2 + l * D, (void*)q_stream,
                                                 q_stream, maskbuf, QROWS, D, FF);
  }

  head_kernel<<<KVROWS / 4, 256, 0, stream>>>(enc, head_W, head_b, out);
  overwrite_kernel<<<QROWS, 64, 0, stream>>>(q_stream, idxbuf, maskbuf, head_W,
                                             head_b, out);
}

// Round 3
// 329.543 us; speedup vs baseline: 41.7516x; 1.4894x over previous
//
#include <hip/hip_runtime.h>
#include <cmath>

constexpr int B = 2, L = 4096, D = 256, H = 8, NC = 3;
constexpr int TOP_N = 8, R = 32;
constexpr int LS = 1000, LE = 3000;
constexpr int NL = 2;
constexpr int FF = 4 * D;                        // 1024
constexpr int Q_MAX = 2 * TOP_N * (2 * R + 1);   // 1040
constexpr int HD = D / H;                        // 32
constexpr int QROWS = B * Q_MAX;                 // 2080
constexpr int KVROWS = B * L;                    // 8192
constexpr int NQT = (Q_MAX + 31) / 32;           // 33 q-tiles of 32
constexpr int NREG = LE - LS;                    // 2000

typedef __attribute__((ext_vector_type(8))) short bf16x8;
typedef __attribute__((ext_vector_type(4))) float f32x4;
typedef __attribute__((ext_vector_type(4))) int i32x4;
typedef unsigned short u16;

union fr {
  bf16x8 h;
  i32x4 i;
};

__device__ __forceinline__ u16 f2bs(float f) {
  unsigned int u = __float_as_uint(f);
  unsigned int r = u + 0x7fffu + ((u >> 16) & 1u);
  return (u16)(r >> 16);
}
__device__ __forceinline__ float bs2f(u16 s) {
  return __uint_as_float(((unsigned int)s) << 16);
}
__device__ __forceinline__ float gelu_exact(float x) {
  return 0.5f * x * (1.f + erff(x * 0.70710678118654752440f));
}
__device__ __forceinline__ unsigned cvt_pk(float lo, float hi) {
  unsigned r;
  asm("v_cvt_pk_bf16_f32 %0, %1, %2" : "=v"(r) : "v"(lo), "v"(hi));
  return r;
}

// ---------------------------------------------------------------------------
// Vicinity selection. One 1024-thread block per batch.
// Top-8 per channel via iterative extract (shfl reduce), then bitmap+scan
// dedup (output order is irrelevant to the final result: any permutation of
// unique positions with mask=1 produces the same output).
// ---------------------------------------------------------------------------
__global__ __launch_bounds__(1024) void select_kernel(
    const float* __restrict__ logits, int* __restrict__ idx_out,
    int* __restrict__ mask_out) {
  int b = blockIdx.x;
  int tid = threadIdx.x;
  __shared__ float vv[2][NREG];
  __shared__ int centers[2 * TOP_N];
  __shared__ unsigned present[L / 32];
  __shared__ float wred[16];
  __shared__ int wredi[16];
  __shared__ int offs[128];
  __shared__ int wtot[2];

  for (int p = tid; p < NREG; p += 1024) {
    const float* lg = logits + ((long)b * L + LS + p) * NC;
    float x0 = lg[0], x1 = lg[1], x2 = lg[2];
    float m = fmaxf(x0, fmaxf(x1, x2));
    float lse = m + logf(expf(x0 - m) + expf(x1 - m) + expf(x2 - m));
    vv[0][p] = x2 - lse;  // don
    vv[1][p] = x1 - lse;  // acc
  }
  if (tid < 128) present[tid] = 0;
  __syncthreads();

  for (int sel = 0; sel < 2; ++sel) {
    for (int t = 0; t < TOP_N; ++t) {
      float bv = -INFINITY;
      int bi = 0x7fffffff;
      for (int p = tid; p < NREG; p += 1024) {
        float x = vv[sel][p];
        if (x > bv || (x == bv && p < bi)) { bv = x; bi = p; }
      }
#pragma unroll
      for (int off = 32; off; off >>= 1) {
        float ov = __shfl_xor(bv, off, 64);
        int oi = __shfl_xor(bi, off, 64);
        if (ov > bv || (ov == bv && oi < bi)) { bv = ov; bi = oi; }
      }
      if ((tid & 63) == 0) { wred[tid >> 6] = bv; wredi[tid >> 6] = bi; }
      __syncthreads();
      if (tid < 64) {
        bv = (tid < 16) ? wred[tid] : -INFINITY;
        bi = (tid < 16) ? wredi[tid] : 0x7fffffff;
#pragma unroll
        for (int off = 8; off; off >>= 1) {
          float ov = __shfl_xor(bv, off, 64);
          int oi = __shfl_xor(bi, off, 64);
          if (ov > bv || (ov == bv && oi < bi)) { bv = ov; bi = oi; }
        }
        if (tid == 0) {
          centers[sel * TOP_N + t] = LS + bi;
          vv[sel][bi] = -INFINITY;
        }
      }
      __syncthreads();
    }
  }

  for (int j = tid; j < Q_MAX; j += 1024) {
    int c = centers[j / (2 * R + 1)];
    int off = j % (2 * R + 1) - R;
    int v = c + off;
    v = v < 0 ? 0 : (v > L - 1 ? L - 1 : v);
    atomicOr(&present[v >> 5], 1u << (v & 31));
  }
  __syncthreads();

  int cnt = (tid < 128) ? __popc(present[tid]) : 0;
  if (tid < 128) {
    int x = cnt;
#pragma unroll
    for (int off = 1; off < 64; off <<= 1) {
      int o = __shfl_up(x, off, 64);
      if ((tid & 63) >= off) x += o;
    }
    if ((tid & 63) == 63) wtot[tid >> 6] = x;
    offs[tid] = x - cnt;
  }
  __syncthreads();
  int total = wtot[0] + wtot[1];
  if (tid < 128) {
    int base = offs[tid] + ((tid >= 64) ? wtot[0] : 0);
    unsigned mword = present[tid];
    while (mword) {
      int i = __ffs(mword) - 1;
      mword &= mword - 1;
      idx_out[b * Q_MAX + base] = tid * 32 + i;
      mask_out[b * Q_MAX + base] = 1;
      ++base;
    }
  }
  for (int j = total + tid; j < Q_MAX; j += 1024) {
    idx_out[b * Q_MAX + j] = L;
    mask_out[b * Q_MAX + j] = 0;
  }
}

// ---------------------------------------------------------------------------
// Gather q_stream rows (pad row -> zeros)
// ---------------------------------------------------------------------------
__global__ __launch_bounds__(256) void gather_kernel(
    const float* __restrict__ enc, const int* __restrict__ idx,
    float* __restrict__ q_stream) {
  int row = blockIdx.x;
  int b = row / Q_MAX;
  int p = idx[row];
  float v = 0.f;
  if (p < L) v = enc[((long)b * L + p) * D + threadIdx.x];
  q_stream[(long)row * D + threadIdx.x] = v;
}

// ---------------------------------------------------------------------------
// LayerNorm fp32 in -> bf16 out (single gamma/beta)
// ---------------------------------------------------------------------------
__global__ __launch_bounds__(256) void ln_bf16(
    const float* __restrict__ in, u16* __restrict__ out,
    const float* __restrict__ gg, const float* __restrict__ bb) {
  long row = blockIdx.x;
  int tid = threadIdx.x;
  float x = in[row * D + tid];
  float s1 = x, s2 = x * x;
#pragma unroll
  for (int off = 32; off; off >>= 1) {
    s1 += __shfl_xor(s1, off, 64);
    s2 += __shfl_xor(s2, off, 64);
  }
  __shared__ float p1[4], p2[4];
  int w = tid >> 6;
  if ((tid & 63) == 0) { p1[w] = s1; p2[w] = s2; }
  __syncthreads();
  s1 = p1[0] + p1[1] + p1[2] + p1[3];
  s2 = p2[0] + p2[1] + p2[2] + p2[3];
  float mean = s1 * (1.f / D);
  float var = fmaxf(s2 * (1.f / D) - mean * mean, 0.f);
  float r = rsqrtf(var + 1e-5f);
  out[row * D + tid] = f2bs((x - mean) * r * gg[tid] + bb[tid]);
}

// LayerNorm of enc with BOTH layers' gamma/beta -> two bf16 outputs
__global__ __launch_bounds__(256) void ln_kv2(
    const float* __restrict__ in, u16* __restrict__ o0, u16* __restrict__ o1,
    const float* __restrict__ g) {  // g = ln_kv_g; beta = g + NL*D? passed sep
  // g layout: [g0 | g1], beta passed via second pointer below
  long row = blockIdx.x;
  int tid = threadIdx.x;
  float x = in[row * D + tid];
  float s1 = x, s2 = x * x;
#pragma unroll
  for (int off = 32; off; off >>= 1) {
    s1 += __shfl_xor(s1, off, 64);
    s2 += __shfl_xor(s2, off, 64);
  }
  __shared__ float p1[4], p2[4];
  int w = tid >> 6;
  if ((tid & 63) == 0) { p1[w] = s1; p2[w] = s2; }
  __syncthreads();
  s1 = p1[0] + p1[1] + p1[2] + p1[3];
  s2 = p2[0] + p2[1] + p2[2] + p2[3];
  float mean = s1 * (1.f / D);
  float var = fmaxf(s2 * (1.f / D) - mean * mean, 0.f);
  float r = rsqrtf(var + 1e-5f);
  float xn = (x - mean) * r;
  const float* bvec = g + 2 * D;  // caller packs [g0,g1,b0,b1] contiguously? no
  (void)bvec;
  o0[row * D + tid] = f2bs(xn * g[tid] + g[2 * D + tid]);
  o1[row * D + tid] = f2bs(xn * g[D + tid] + g[3 * D + tid]);
}

// Pack [g0,g1,b0,b1] into one buffer so ln_kv2 takes a single pointer
__global__ __launch_bounds__(256) void pack_lnkv(
    const float* __restrict__ g, const float* __restrict__ bb,
    float* __restrict__ dst) {
  int t = blockIdx.x * 256 + threadIdx.x;
  if (t < 2 * D) dst[t] = g[t];
  else if (t < 4 * D) dst[t] = bb[t - 2 * D];
}

// ---------------------------------------------------------------------------
// Batched weight transpose+bf16: all NL layers, all 6 matrices, one dispatch.
// WT layer layout (shorts): Wk[0], Wv[DD], Wq[2DD], Wo[3DD], W1[4DD], W2[4DD+DFF]
// ---------------------------------------------------------------------------
__global__ __launch_bounds__(256) void transpose_all(
    const float* __restrict__ Wq_, const float* __restrict__ Wk_,
    const float* __restrict__ Wv_, const float* __restrict__ Wo_,
    const float* __restrict__ W1_, const float* __restrict__ W2_,
    u16* __restrict__ WT) {
  const long DD = (long)D * D, DFF = (long)D * FF;
  const long LSTR = 4 * DD + 2 * DFF;
  long t = (long)blockIdx.x * 256 + threadIdx.x;
  if (t >= NL * LSTR) return;
  int l = (int)(t / LSTR);
  long r = t - (long)l * LSTR;
  const float* src;
  long dstbase, e;
  int K_, N_;
  if (r < 4 * DD) {
    int which = (int)(r >> 16);  // DD = 65536
    e = r & (DD - 1);
    K_ = D; N_ = D;
    src = (which == 0 ? Wk_ : which == 1 ? Wv_ : which == 2 ? Wq_ : Wo_) +
          (long)l * DD;
    dstbase = l * LSTR + which * DD;
  } else if (r < 4 * DD + DFF) {
    e = r - 4 * DD;
    K_ = D; N_ = FF;
    src = W1_ + (long)l * DFF;
    dstbase = l * LSTR + 4 * DD;
  } else {
    e = r - 4 * DD - DFF;
    K_ = FF; N_ = D;
    src = W2_ + (long)l * DFF;
    dstbase = l * LSTR + 4 * DD + DFF;
  }
  int k = (int)(e / N_), n = (int)(e % N_);
  WT[dstbase + (long)n * K_ + k] = f2bs(src[e]);
}

// ---------------------------------------------------------------------------
// bf16 MFMA GEMM: C[M,N] = epi(A[M,K] @ B + bias), B given as BT[N,K] bf16.
// 64x64 tile, BK=32, 4 waves. EPI 0: bias (bf16 out); 1: gelu (bf16 out);
// 2: resid+mask (f32 out); 3: bias + per-head transposed bf16 out
//    Vt[((b*H+h)*HD+d)*L + key]  (for attention V).
// ---------------------------------------------------------------------------
template <int EPI>
__global__ __launch_bounds__(256) void gemm_mfma(
    const u16* __restrict__ A, const u16* __restrict__ BT,
    const float* __restrict__ bias, void* __restrict__ Cv,
    const float* __restrict__ resid, const int* __restrict__ mask, int M,
    int N, int K) {
  __shared__ short As[64][40];
  __shared__ short Bs[64][40];
  int bm = blockIdx.y * 64, bn = blockIdx.x * 64;
  int tid = threadIdx.x;
  int lane = tid & 63, w = tid >> 6;
  int g = lane >> 4, li = lane & 15;
  int wr = w >> 1, wc = w & 1;
  f32x4 acc[2][2] = {};

  int srow = tid >> 2, skc = (tid & 3) * 8;
  for (int k0 = 0; k0 < K; k0 += 32) {
    {
      int grow = bm + srow;
      bf16x8 av = {};
      if (grow < M)
        av = *reinterpret_cast<const bf16x8*>(A + (long)grow * K + k0 + skc);
      *reinterpret_cast<bf16x8*>(&As[srow][skc]) = av;
      bf16x8 bv = *reinterpret_cast<const bf16x8*>(
          BT + (long)(bn + srow) * K + k0 + skc);
      *reinterpret_cast<bf16x8*>(&Bs[srow][skc]) = bv;
    }
    __syncthreads();
    bf16x8 a0 = *reinterpret_cast<const bf16x8*>(&As[wr * 32 + li][g * 8]);
    bf16x8 a1 = *reinterpret_cast<const bf16x8*>(&As[wr * 32 + 16 + li][g * 8]);
    bf16x8 b0 = *reinterpret_cast<const bf16x8*>(&Bs[wc * 32 + li][g * 8]);
    bf16x8 b1 = *reinterpret_cast<const bf16x8*>(&Bs[wc * 32 + 16 + li][g * 8]);
    acc[0][0] = __builtin_amdgcn_mfma_f32_16x16x32_bf16(a0, b0, acc[0][0], 0, 0, 0);
    acc[0][1] = __builtin_amdgcn_mfma_f32_16x16x32_bf16(a0, b1, acc[0][1], 0, 0, 0);
    acc[1][0] = __builtin_amdgcn_mfma_f32_16x16x32_bf16(a1, b0, acc[1][0], 0, 0, 0);
    acc[1][1] = __builtin_amdgcn_mfma_f32_16x16x32_bf16(a1, b1, acc[1][1], 0, 0, 0);
    __syncthreads();
  }

  if constexpr (EPI == 3) {
    __shared__ u16 Ct[64][72];
#pragma unroll
    for (int mr = 0; mr < 2; ++mr)
#pragma unroll
      for (int nr = 0; nr < 2; ++nr)
#pragma unroll
        for (int r = 0; r < 4; ++r) {
          int rowL = wr * 32 + mr * 16 + g * 4 + r;
          int colL = wc * 32 + nr * 16 + li;
          Ct[colL][rowL] = f2bs(acc[mr][nr][r] + bias[bn + colL]);
        }
    __syncthreads();
    int colL = tid >> 2, rseg = (tid & 3) * 16;
    int gcol = bn + colL;
    int hh = gcol >> 5, dd = gcol & (HD - 1);
    int grow = bm + rseg;
    int bb2 = grow >> 12, key = grow & (L - 1);
    u16* dst = (u16*)Cv + ((long)(bb2 * H + hh) * HD + dd) * L + key;
    *reinterpret_cast<bf16x8*>(dst) =
        *reinterpret_cast<const bf16x8*>(&Ct[colL][rseg]);
    *reinterpret_cast<bf16x8*>(dst + 8) =
        *reinterpret_cast<const bf16x8*>(&Ct[colL][rseg + 8]);
  } else {
#pragma unroll
    for (int mr = 0; mr < 2; ++mr)
#pragma unroll
      for (int nr = 0; nr < 2; ++nr)
#pragma unroll
        for (int r = 0; r < 4; ++r) {
          int row = bm + wr * 32 + mr * 16 + g * 4 + r;
          int col = bn + wc * 32 + nr * 16 + li;
          if (row >= M) continue;
          float v = acc[mr][nr][r] + bias[col];
          if (EPI == 1) v = gelu_exact(v);
          if (EPI == 2) {
            v += resid[(long)row * N + col];
            v = mask[row] ? v : 0.f;
            ((float*)Cv)[(long)row * N + col] = v;
          } else {
            ((u16*)Cv)[(long)row * N + col] = f2bs(v);
          }
        }
  }
}

// ---------------------------------------------------------------------------
// Fused flash attention, register-resident, split-K.
// Block = 256 thr (4 waves) per (b,h,32-query tile); wave w covers keys
// [w*L/4,(w+1)*L/4). K frags load global->reg; V^T frags from pre-transposed
// Vt with the SAME key map as P^T (permutation cancels). exp2-domain softmax
// (scale*log2e folded into Q). LDS only for the final 4-way combine.
// ---------------------------------------------------------------------------
__global__ __launch_bounds__(256) void attn_mfma(
    const u16* __restrict__ Qb, const u16* __restrict__ Kb,
    const u16* __restrict__ Vt, u16* __restrict__ AO) {
  int bid = blockIdx.x;
  int qt = bid % NQT;
  int bh = bid / NQT;
  int h = bh % H;
  int b = bh / H;
  int tid = threadIdx.x, w = tid >> 6, lane = tid & 63;
  int g = lane >> 4, li = lane & 15;

  __shared__ float accs[4][32][33];
  __shared__ float msh[4][32];
  __shared__ float dsh[4][32];

  fr qf0, qf1;
  {
    const float QSC = 0.25509836048f;  // (1/sqrt(32)) * log2(e)
#pragma unroll
    for (int qb = 0; qb < 2; ++qb) {
      int qrow = qt * 32 + qb * 16 + li;
      if (qrow >= Q_MAX) qrow = Q_MAX - 1;
      bf16x8 raw = *reinterpret_cast<const bf16x8*>(
          Qb + ((long)(b * Q_MAX + qrow)) * D + h * HD + g * 8);
      fr& qf = qb ? qf1 : qf0;
#pragma unroll
      for (int j = 0; j < 4; ++j)
        qf.i[j] = (int)cvt_pk(bs2f((u16)raw[2 * j]) * QSC,
                              bs2f((u16)raw[2 * j + 1]) * QSC);
    }
  }

  f32x4 acc00 = {}, acc01 = {}, acc10 = {}, acc11 = {};
  float m0 = -INFINITY, m1 = -INFINITY, d0 = 0.f, d1 = 0.f;
  const f32x4 z = {};

  const u16* kp = Kb + ((long)b * L) * D + h * HD + g * 8;
  const u16* vp = Vt + ((long)(b * H + h)) * HD * (long)L;

  int kend = (w + 1) * (L / 4);
  for (int kb = w * (L / 4); kb < kend; kb += 32) {
    bf16x8 kf0 = *reinterpret_cast<const bf16x8*>(kp + (long)(kb + li) * D);
    bf16x8 kf1 = *reinterpret_cast<const bf16x8*>(kp + (long)(kb + 16 + li) * D);
    uint2 va0 = *reinterpret_cast<const uint2*>(vp + (long)li * L + kb + 4 * g);
    uint2 vb0 = *reinterpret_cast<const uint2*>(vp + (long)li * L + kb + 16 + 4 * g);
    uint2 va1 = *reinterpret_cast<const uint2*>(vp + (long)(16 + li) * L + kb + 4 * g);
    uint2 vb1 = *reinterpret_cast<const uint2*>(vp + (long)(16 + li) * L + kb + 16 + 4 * g);

    f32x4 s00 = __builtin_amdgcn_mfma_f32_16x16x32_bf16(kf0, qf0.h, z, 0, 0, 0);
    f32x4 s01 = __builtin_amdgcn_mfma_f32_16x16x32_bf16(kf0, qf1.h, z, 0, 0, 0);
    f32x4 s10 = __builtin_amdgcn_mfma_f32_16x16x32_bf16(kf1, qf0.h, z, 0, 0, 0);
    f32x4 s11 = __builtin_amdgcn_mfma_f32_16x16x32_bf16(kf1, qf1.h, z, 0, 0, 0);

    // ---- q-block 0 softmax (keys: s00 -> 4g+r, s10 -> 16+4g+r, query li)
    float t0 = fmaxf(fmaxf(fmaxf(s00[0], s00[1]), fmaxf(s00[2], s00[3])),
                     fmaxf(fmaxf(s10[0], s10[1]), fmaxf(s10[2], s10[3])));
    t0 = fmaxf(t0, __shfl_xor(t0, 16, 64));
    t0 = fmaxf(t0, __shfl_xor(t0, 32, 64));
    float nm0 = fmaxf(m0, t0);
    float sc0 = exp2f(m0 - nm0);
    m0 = nm0;
    float p00[4], p10[4], ts0 = 0.f;
#pragma unroll
    for (int r = 0; r < 4; ++r) {
      p00[r] = exp2f(s00[r] - nm0);
      p10[r] = exp2f(s10[r] - nm0);
      ts0 += p00[r] + p10[r];
    }
    ts0 += __shfl_xor(ts0, 16, 64);
    ts0 += __shfl_xor(ts0, 32, 64);
    d0 = d0 * sc0 + ts0;
    fr pf0;
    pf0.i[0] = (int)cvt_pk(p00[0], p00[1]);
    pf0.i[1] = (int)cvt_pk(p00[2], p00[3]);
    pf0.i[2] = (int)cvt_pk(p10[0], p10[1]);
    pf0.i[3] = (int)cvt_pk(p10[2], p10[3]);

    // ---- q-block 1
    float t1 = fmaxf(fmaxf(fmaxf(s01[0], s01[1]), fmaxf(s01[2], s01[3])),
                     fmaxf(fmaxf(s11[0], s11[1]), fmaxf(s11[2], s11[3])));
    t1 = fmaxf(t1, __shfl_xor(t1, 16, 64));
    t1 = fmaxf(t1, __shfl_xor(t1, 32, 64));
    float nm1 = fmaxf(m1, t1);
    float sc1 = exp2f(m1 - nm1);
    m1 = nm1;
    float p01[4], p11[4], ts1 = 0.f;
#pragma unroll
    for (int r = 0; r < 4; ++r) {
      p01[r] = exp2f(s01[r] - nm1);
      p11[r] = exp2f(s11[r] - nm1);
      ts1 += p01[r] + p11[r];
    }
    ts1 += __shfl_xor(ts1, 16, 64);
    ts1 += __shfl_xor(ts1, 32, 64);
    d1 = d1 * sc1 + ts1;
    fr pf1;
    pf1.i[0] = (int)cvt_pk(p01[0], p01[1]);
    pf1.i[1] = (int)cvt_pk(p01[2], p01[3]);
    pf1.i[2] = (int)cvt_pk(p11[0], p11[1]);
    pf1.i[3] = (int)cvt_pk(p11[2], p11[3]);

#pragma unroll
    for (int r = 0; r < 4; ++r) {
      acc00[r] *= sc0;
      acc10[r] *= sc0;
      acc01[r] *= sc1;
      acc11[r] *= sc1;
    }
    fr v0, v1;
    v0.i = (i32x4){(int)va0.x, (int)va0.y, (int)vb0.x, (int)vb0.y};
    v1.i = (i32x4){(int)va1.x, (int)va1.y, (int)vb1.x, (int)vb1.y};
    acc00 = __builtin_amdgcn_mfma_f32_16x16x32_bf16(v0.h, pf0.h, acc00, 0, 0, 0);
    acc01 = __builtin_amdgcn_mfma_f32_16x16x32_bf16(v0.h, pf1.h, acc01, 0, 0, 0);
    acc10 = __builtin_amdgcn_mfma_f32_16x16x32_bf16(v1.h, pf0.h, acc10, 0, 0, 0);
    acc11 = __builtin_amdgcn_mfma_f32_16x16x32_bf16(v1.h, pf1.h, acc11, 0, 0, 0);
  }

  // ---- cross-wave combine
#pragma unroll
  for (int r = 0; r < 4; ++r) {
    accs[w][g * 4 + r][li] = acc00[r];
    accs[w][g * 4 + r][16 + li] = acc01[r];
    accs[w][16 + g * 4 + r][li] = acc10[r];
    accs[w][16 + g * 4 + r][16 + li] = acc11[r];
  }
  if (g == 0) {
    msh[w][li] = m0;
    msh[w][16 + li] = m1;
    dsh[w][li] = d0;
    dsh[w][16 + li] = d1;
  }
  __syncthreads();

  int q = tid & 31, dbase = (tid >> 5) * 4;
  float mw0 = msh[0][q], mw1 = msh[1][q], mw2 = msh[2][q], mw3 = msh[3][q];
  float M = fmaxf(fmaxf(mw0, mw1), fmaxf(mw2, mw3));
  float w0 = exp2f(mw0 - M), w1 = exp2f(mw1 - M), w2 = exp2f(mw2 - M),
        w3 = exp2f(mw3 - M);
  float Den = w0 * dsh[0][q] + w1 * dsh[1][q] + w2 * dsh[2][q] + w3 * dsh[3][q];
  float inv = 1.f / Den;
  int qrow = qt * 32 + q;
  if (qrow < Q_MAX) {
    unsigned pk[2];
#pragma unroll
    for (int half = 0; half < 2; ++half) {
      float o0 = accs[0][dbase + 2 * half][q] * w0 + accs[1][dbase + 2 * half][q] * w1 +
                 accs[2][dbase + 2 * half][q] * w2 + accs[3][dbase + 2 * half][q] * w3;
      float o1 = accs[0][dbase + 2 * half + 1][q] * w0 + accs[1][dbase + 2 * half + 1][q] * w1 +
                 accs[2][dbase + 2 * half + 1][q] * w2 + accs[3][dbase + 2 * half + 1][q] * w3;
      pk[half] = cvt_pk(o0 * inv, o1 * inv);
    }
    uint2 ov = {pk[0], pk[1]};
    *reinterpret_cast<uint2*>(AO + ((long)(b * Q_MAX + qrow)) * D + h * HD + dbase) = ov;
  }
}

// ---------------------------------------------------------------------------
// Head over all rows; one wave per row
// ---------------------------------------------------------------------------
__global__ __launch_bounds__(256) void head_kernel(
    const float* __restrict__ enc, const float* __restrict__ hW,
    const float* __restrict__ hb, float* __restrict__ out) {
  int row = blockIdx.x * 4 + (threadIdx.x >> 6);
  int lane = threadIdx.x & 63;
  const float4 a = *reinterpret_cast<const float4*>(enc + (long)row * D + lane * 4);
  float c0 = 0.f, c1 = 0.f, c2 = 0.f;
  const float av[4] = {a.x, a.y, a.z, a.w};
#pragma unroll
  for (int i = 0; i < 4; ++i) {
    int k = lane * 4 + i;
    c0 += av[i] * hW[k * 3];
    c1 += av[i] * hW[k * 3 + 1];
    c2 += av[i] * hW[k * 3 + 2];
  }
#pragma unroll
  for (int off = 32; off; off >>= 1) {
    c0 += __shfl_down(c0, off, 64);
    c1 += __shfl_down(c1, off, 64);
    c2 += __shfl_down(c2, off, 64);
  }
  if (lane == 0) {
    out[(long)row * 3] = c0 + hb[0];
    out[(long)row * 3 + 1] = c1 + hb[1];
    out[(long)row * 3 + 2] = c2 + hb[2];
  }
}

// ---------------------------------------------------------------------------
// Overwrite selected rows with head(q_stream). One wave per slot.
// ---------------------------------------------------------------------------
__global__ __launch_bounds__(64) void overwrite_kernel(
    const float* __restrict__ q_stream, const int* __restrict__ idx,
    const int* __restrict__ mask, const float* __restrict__ hW,
    const float* __restrict__ hb, float* __restrict__ out) {
  int j = blockIdx.x;
  if (!mask[j]) return;
  int b = j / Q_MAX;
  int p = idx[j];
  int lane = threadIdx.x;
  const float* a = q_stream + (long)j * D;
  float a0 = a[lane], a1 = a[lane + 64], a2 = a[lane + 128],
        a3 = a[lane + 192];
  for (int c = 0; c < 3; ++c) {
    float s = a0 * hW[lane * 3 + c] + a1 * hW[(lane + 64) * 3 + c] +
              a2 * hW[(lane + 128) * 3 + c] + a3 * hW[(lane + 192) * 3 + c];
    for (int off = 32; off > 0; off >>= 1) s += __shfl_down(s, off, 64);
    if (lane == 0) out[((long)b * L + p) * 3 + c] = s + hb[c];
  }
}

// ---------------------------------------------------------------------------
extern "C" void kernel_launch(void* const* d_in, const int* in_sizes, int n_in,
                              void* d_out, int out_size, void* d_ws,
                              size_t ws_size, hipStream_t stream) {
  const float* enc = (const float*)d_in[0];
  const float* clog = (const float*)d_in[1];
  const float* ln_q_g = (const float*)d_in[2];
  const float* ln_q_b = (const float*)d_in[3];
  const float* ln_kv_g = (const float*)d_in[4];
  const float* ln_kv_b = (const float*)d_in[5];
  const float* Wq = (const float*)d_in[6];
  const float* bq = (const float*)d_in[7];
  const float* Wk = (const float*)d_in[8];
  const float* bk = (const float*)d_in[9];
  const float* Wv = (const float*)d_in[10];
  const float* bv = (const float*)d_in[11];
  const float* Wo = (const float*)d_in[12];
  const float* bo = (const float*)d_in[13];
  const float* ffn_g = (const float*)d_in[14];
  const float* ffn_b = (const float*)d_in[15];
  const float* W1 = (const float*)d_in[16];
  const float* b1 = (const float*)d_in[17];
  const float* W2 = (const float*)d_in[18];
  const float* b2 = (const float*)d_in[19];
  const float* head_W = (const float*)d_in[20];
  const float* head_b = (const float*)d_in[21];
  float* out = (float*)d_out;

  char* ws = (char*)d_ws;
  float* q_stream = (float*)ws;            ws += (long)QROWS * D * 4;
  u16* kvl0 = (u16*)ws;                    ws += (long)KVROWS * D * 2;
  u16* kvl1 = (u16*)ws;                    ws += (long)KVROWS * D * 2;
  u16* Kbuf = (u16*)ws;                    ws += (long)KVROWS * D * 2;
  u16* Vtbuf = (u16*)ws;                   ws += (long)B * H * HD * L * 2;
  u16* q_ln = (u16*)ws;                    ws += (long)QROWS * D * 2;
  u16* Qbuf = (u16*)ws;                    ws += (long)QROWS * D * 2;
  u16* AObuf = (u16*)ws;                   ws += (long)QROWS * D * 2;
  u16* H1buf = (u16*)ws;                   ws += (long)QROWS * FF * 2;
  u16* WT = (u16*)ws;                      ws += (long)NL * (4 * D * D + 2 * D * FF) * 2;
  float* lnkv_pack = (float*)ws;           ws += 4 * D * 4;
  int* idxbuf = (int*)ws;                  ws += QROWS * 4;
  int* maskbuf = (int*)ws;

  const long DD = (long)D * D, DFF = (long)D * FF;
  const long LSTR = 4 * DD + 2 * DFF;

  transpose_all<<<(int)((NL * LSTR + 255) / 256), 256, 0, stream>>>(
      Wq, Wk, Wv, Wo, W1, W2, WT);
  pack_lnkv<<<(4 * D + 255) / 256, 256, 0, stream>>>(ln_kv_g, ln_kv_b, lnkv_pack);
  ln_kv2<<<KVROWS, 256, 0, stream>>>(enc, kvl0, kvl1, lnkv_pack);
  select_kernel<<<B, 1024, 0, stream>>>(clog, idxbuf, maskbuf);
  gather_kernel<<<QROWS, 256, 0, stream>>>(enc, idxbuf, q_stream);

  for (int l = 0; l < NL; ++l) {
    u16* base = WT + l * LSTR;
    u16* kv_ln = (l == 0) ? kvl0 : kvl1;

    ln_bf16<<<QROWS, 256, 0, stream>>>(q_stream, q_ln, ln_q_g + l * D, ln_q_b + l * D);

    dim3 gKV(D / 64, KVROWS / 64);
    gemm_mfma<0><<<gKV, 256, 0, stream>>>(kv_ln, base, bk + l * D,
                                          (void*)Kbuf, nullptr, nullptr,
                                          KVROWS, D, D);
    gemm_mfma<3><<<gKV, 256, 0, stream>>>(kv_ln, base + DD, bv + l * D,
                                          (void*)Vtbuf, nullptr, nullptr,
                                          KVROWS, D, D);
    dim3 gQ(D / 64, (QROWS + 63) / 64);
    gemm_mfma<0><<<gQ, 256, 0, stream>>>(q_ln, base + 2 * DD, bq + l * D,
                                         (void*)Qbuf, nullptr, nullptr,
                                         QROWS, D, D);

    attn_mfma<<<B * H * NQT, 256, 0, stream>>>(Qbuf, Kbuf, Vtbuf, AObuf);

    gemm_mfma<2><<<gQ, 256, 0, stream>>>(AObuf, base + 3 * DD, bo + l * D,
                                         (void*)q_stream, q_stream, maskbuf,
                                         QROWS, D, D);

    ln_bf16<<<QROWS, 256, 0, stream>>>(q_stream, q_ln, ffn_g + l * D, ffn_b + l * D);
    dim3 gF1(FF / 64, (QROWS + 63) / 64);
    gemm_mfma<1><<<gF1, 256, 0, stream>>>(q_ln, base + 4 * DD, b1 + l * FF,
                                          (void*)H1buf, nullptr, nullptr,
                                          QROWS, FF, D);
    dim3 gF2(D / 64, (QROWS + 63) / 64);
    gemm_mfma<2><<<gF2, 256, 0, stream>>>(H1buf, base + 4 * DD + DFF,
                                          b2 + l * D, (void*)q_stream,
                                          q_stream, maskbuf, QROWS, D, FF);
  }

  head_kernel<<<KVROWS / 4, 256, 0, stream>>>(enc, head_W, head_b, out);
  overwrite_kernel<<<QROWS, 64, 0, stream>>>(q_stream, idxbuf, maskbuf, head_W,
                                             head_b, out);
}